// Round 1
// baseline (914.600 us; speedup 1.0000x reference)
//
#include <hip/hip_runtime.h>

// GCN 3-layer forward on MI355X.
// Structure per layer:
//   GEMM (H = X@W, fused epilogue AGG = H/deg + bias)   [tiled f32, reg-blocked]
//   edge scatter: AGG[dst] += H[src] * rsd[src]*rsd[dst] [f32 atomics]
//   ReLU (layers 1,2)
// deg/rsd computed once (shared by all layers).

#define K_DIM 128

__global__ void k_deg_init(float* __restrict__ deg, int n) {
    int i = blockIdx.x * 256 + threadIdx.x;
    if (i < n) deg[i] = 1.0f;
}

__global__ void k_deg_count(const int* __restrict__ dst, float* __restrict__ deg, int E) {
    int e = blockIdx.x * 256 + threadIdx.x;
    if (e < E) atomicAdd(&deg[dst[e]], 1.0f);
}

__global__ void k_rsd(const float* __restrict__ deg, float* __restrict__ rsd, int n) {
    int i = blockIdx.x * 256 + threadIdx.x;
    if (i < n) rsd[i] = rsqrtf(deg[i]);
}

// Tiled GEMM: X[nrows,128] @ W[128,COUT] -> H[nrows,COUT]
// Fused epilogue: AGG[row,c] = H[row,c] * (1/deg[row]) + bias[c]
// BM=64 rows/block, full COUT width, BK=32 k-tile, 256 threads.
// In-place safe when AGG aliases X: each block reads only its own rows (all
// global reads precede the epilogue stores within the block).
template <int COUT>
__launch_bounds__(256)
__global__ void k_gemm(const float* __restrict__ X, const float* __restrict__ W,
                       const float* __restrict__ bias, const float* __restrict__ deg,
                       float* __restrict__ H, float* __restrict__ AGG, int nrows) {
    constexpr int BM = 64, BK = 32, TN = 4;
    constexpr int CG = COUT / TN;   // column groups: 32 (COUT=128) or 16 (COUT=64)
    constexpr int RG = 256 / CG;    // row groups: 8 or 16
    constexpr int TM = BM / RG;     // 8 or 4
    constexpr int BMP = 68;         // pad 64->68: keeps float4 alignment, cuts write conflicts to 4-way

    __shared__ float Xs[BK][BMP];   // transposed: Xs[k][row]
    __shared__ float Ws[BK][COUT];

    const int tid = threadIdx.x;
    const int tx = tid % CG;        // column group
    const int ty = tid / CG;        // row group
    const int r0 = blockIdx.x * BM;

    float acc[TM][TN];
#pragma unroll
    for (int i = 0; i < TM; ++i)
#pragma unroll
        for (int j = 0; j < TN; ++j) acc[i][j] = 0.0f;

    const float4 bfrag = *(const float4*)&bias[tx * TN];

    for (int kb = 0; kb < K_DIM; kb += BK) {
        __syncthreads();
        // X tile: 64 rows x 32 k. thread: r=tid/8 (0..31), kq=tid%8; 2 row passes.
        {
            int r = tid >> 3, kq = tid & 7;
#pragma unroll
            for (int p = 0; p < 2; ++p) {
                int rr = r + p * 32;
                int grow = r0 + rr;
                if (grow >= nrows) grow = nrows - 1;  // clamp; stores are guarded
                float4 v = *(const float4*)&X[(size_t)grow * K_DIM + kb + kq * 4];
                Xs[kq * 4 + 0][rr] = v.x;
                Xs[kq * 4 + 1][rr] = v.y;
                Xs[kq * 4 + 2][rr] = v.z;
                Xs[kq * 4 + 3][rr] = v.w;
            }
        }
        // W tile: 32 k-rows x COUT cols, fully coalesced float4.
        {
            constexpr int F4 = COUT / 4;    // float4s per row: 32 or 16
            constexpr int RP = 256 / F4;    // rows per pass: 8 or 16
            int wq = tid % F4, wr = tid / F4;
#pragma unroll
            for (int p = 0; p < BK / RP; ++p) {
                int krow = wr + p * RP;
                *(float4*)&Ws[krow][wq * 4] =
                    *(const float4*)&W[(size_t)(kb + krow) * COUT + wq * 4];
            }
        }
        __syncthreads();
#pragma unroll
        for (int kk = 0; kk < BK; ++kk) {
            float4 b4 = *(const float4*)&Ws[kk][tx * TN];
            float a[TM];
#pragma unroll
            for (int i = 0; i < TM; i += 4) {
                float4 a4 = *(const float4*)&Xs[kk][ty * TM + i];
                a[i] = a4.x; a[i + 1] = a4.y; a[i + 2] = a4.z; a[i + 3] = a4.w;
            }
#pragma unroll
            for (int i = 0; i < TM; ++i) {
                acc[i][0] += a[i] * b4.x;
                acc[i][1] += a[i] * b4.y;
                acc[i][2] += a[i] * b4.z;
                acc[i][3] += a[i] * b4.w;
            }
        }
    }

    // Epilogue: store H and AGG init (self-loop term + bias).
#pragma unroll
    for (int i = 0; i < TM; ++i) {
        int row = r0 + ty * TM + i;
        if (row < nrows) {
            float invd = 1.0f / deg[row];
            float4 h4 = make_float4(acc[i][0], acc[i][1], acc[i][2], acc[i][3]);
            *(float4*)&H[(size_t)row * COUT + tx * TN] = h4;
            float4 g4 = make_float4(h4.x * invd + bfrag.x, h4.y * invd + bfrag.y,
                                    h4.z * invd + bfrag.z, h4.w * invd + bfrag.w);
            *(float4*)&AGG[(size_t)row * COUT + tx * TN] = g4;
        }
    }
}

// Edge scatter: AGG[dst, c] += H[src, c] * rsd[src]*rsd[dst]
// One thread per (edge, channel). Consecutive threads = consecutive channels
// of one edge -> coalesced gather / same-row atomics.
template <int C>
__global__ void k_scatter(const int* __restrict__ src, const int* __restrict__ dst,
                          const float* __restrict__ rsd, const float* __restrict__ H,
                          float* __restrict__ AGG, int E) {
    constexpr int SH = (C == 128) ? 7 : 6;
    int idx = blockIdx.x * 256 + threadIdx.x;   // < E*C <= 81.92M, fits int
    int e = idx >> SH;
    int c = idx & (C - 1);
    if (e < E) {
        int s = src[e], d = dst[e];
        float coef = rsd[s] * rsd[d];
        atomicAdd(&AGG[(size_t)d * C + c], H[(size_t)s * C + c] * coef);
    }
}

__global__ void k_relu(float* __restrict__ a, int n) {
    int i = blockIdx.x * 256 + threadIdx.x;
    if (i < n) a[i] = fmaxf(a[i], 0.0f);
}

extern "C" void kernel_launch(void* const* d_in, const int* in_sizes, int n_in,
                              void* d_out, int out_size, void* d_ws, size_t ws_size,
                              hipStream_t stream) {
    const float* x  = (const float*)d_in[0];
    const int*   ei = (const int*)d_in[1];
    const float* W1 = (const float*)d_in[2];
    const float* b1 = (const float*)d_in[3];
    const float* W2 = (const float*)d_in[4];
    const float* b2 = (const float*)d_in[5];
    const float* W3 = (const float*)d_in[6];
    const float* b3 = (const float*)d_in[7];

    const int N = in_sizes[0] / K_DIM;   // 50000
    const int E = in_sizes[1] / 2;       // 640000
    const int* srcv = ei;
    const int* dstv = ei + E;

    // Workspace layout (all offsets 256B-aligned):
    char* ws = (char*)d_ws;
    size_t off = 0;
    auto alloc = [&](size_t bytes) {
        char* p = ws + off;
        off += (bytes + 255) & ~(size_t)255;
        return p;
    };
    float* deg  = (float*)alloc((size_t)N * 4);
    float* rsd  = (float*)alloc((size_t)N * 4);
    float* bufH = (float*)alloc((size_t)N * K_DIM * 4);
    float* bufA = (float*)alloc((size_t)N * K_DIM * 4);
    float* out  = (float*)d_out;

    const int gN   = (N + 255) / 256;
    const int gE   = (E + 255) / 256;
    const int gb   = (N + 63) / 64;
    const int gNC  = (N * K_DIM + 255) / 256;
    const int gE128 = (E * 128 + 255) / 256;
    const int gE64  = (E * 64 + 255) / 256;

    // degree (shared by all 3 layers)
    k_deg_init<<<gN, 256, 0, stream>>>(deg, N);
    k_deg_count<<<gE, 256, 0, stream>>>(dstv, deg, E);
    k_rsd<<<gN, 256, 0, stream>>>(deg, rsd, N);

    // layer 1: x -> bufA
    k_gemm<128><<<gb, 256, 0, stream>>>(x, W1, b1, deg, bufH, bufA, N);
    k_scatter<128><<<gE128, 256, 0, stream>>>(srcv, dstv, rsd, bufH, bufA, E);
    k_relu<<<gNC, 256, 0, stream>>>(bufA, N * K_DIM);

    // layer 2: bufA -> bufA (in-place safe per-row GEMM)
    k_gemm<128><<<gb, 256, 0, stream>>>(bufA, W2, b2, deg, bufH, bufA, N);
    k_scatter<128><<<gE128, 256, 0, stream>>>(srcv, dstv, rsd, bufH, bufA, E);
    k_relu<<<gNC, 256, 0, stream>>>(bufA, N * K_DIM);

    // layer 3: bufA -> d_out (COUT=64)
    k_gemm<64><<<gb, 256, 0, stream>>>(bufA, W3, b3, deg, bufH, out, N);
    k_scatter<64><<<gE64, 256, 0, stream>>>(srcv, dstv, rsd, bufH, out, E);
}

// Round 2
// 367.846 us; speedup vs baseline: 2.4864x; 2.4864x over previous
//
#include <hip/hip_runtime.h>

// GCN 3-layer forward on MI355X — round 2: CSR gather-reduce aggregation.
//
// R1 post-mortem: scatter atomics wrote through to HBM (WRITE_SIZE == E*C*4
// exactly), 683 us of 914. This round builds CSR (group edges by dst) once,
// then aggregates with register accumulation: one 32-thread (C=128) or
// 16-thread (C=64) group per node, float4 per thread, single store per output
// element. Bias + self-loop + ReLU fused into the aggregation epilogue.

#define K_DIM 128

// ---------------- degree / CSR build ----------------

__global__ void k_zero_int(int* __restrict__ p, int n) {
    int i = blockIdx.x * 256 + threadIdx.x;
    if (i < n) p[i] = 0;
}

__global__ void k_count(const int* __restrict__ dst, int* __restrict__ cnt, int E) {
    int e = blockIdx.x * 256 + threadIdx.x;
    if (e < E) atomicAdd(&cnt[dst[e]], 1);
}

__global__ void k_norms(const int* __restrict__ cnt, float* __restrict__ rsd,
                        float* __restrict__ invd, int n) {
    int i = blockIdx.x * 256 + threadIdx.x;
    if (i < n) {
        float dg = (float)cnt[i] + 1.0f;   // +1 self-loop
        rsd[i]  = rsqrtf(dg);
        invd[i] = 1.0f / dg;
    }
}

// Per-block inclusive scan (Hillis-Steele, 256 wide); writes exclusive prefix
// to rowptr and block total to bsum.
__global__ void k_scan_block(const int* __restrict__ cnt, int* __restrict__ rowptr,
                             int* __restrict__ bsum, int n) {
    __shared__ int s[256];
    int t = threadIdx.x;
    int i = blockIdx.x * 256 + t;
    int x = (i < n) ? cnt[i] : 0;
    s[t] = x;
    __syncthreads();
#pragma unroll
    for (int d = 1; d < 256; d <<= 1) {
        int v = (t >= d) ? s[t - d] : 0;
        __syncthreads();
        s[t] += v;
        __syncthreads();
    }
    if (i < n) rowptr[i] = s[t] - x;        // exclusive
    if (t == 255) bsum[blockIdx.x] = s[255];
}

// Scan of block sums (nb <= 256), in place -> exclusive prefix.
__global__ void k_scan_bsums(int* __restrict__ bsum, int nb) {
    __shared__ int s[256];
    int t = threadIdx.x;
    int x = (t < nb) ? bsum[t] : 0;
    s[t] = x;
    __syncthreads();
#pragma unroll
    for (int d = 1; d < 256; d <<= 1) {
        int v = (t >= d) ? s[t - d] : 0;
        __syncthreads();
        s[t] += v;
        __syncthreads();
    }
    if (t < nb) bsum[t] = s[t] - x;         // exclusive
}

__global__ void k_scan_add(int* __restrict__ rowptr, int* __restrict__ cursor,
                           const int* __restrict__ bsum, int n, int E) {
    int i = blockIdx.x * 256 + threadIdx.x;
    if (i < n) {
        int v = rowptr[i] + bsum[i >> 8];
        rowptr[i] = v;
        cursor[i] = v;
    }
    if (i == 0) rowptr[n] = E;
}

__global__ void k_fill(const int* __restrict__ src, const int* __restrict__ dst,
                       const float* __restrict__ rsd, int* __restrict__ cursor,
                       int* __restrict__ col, float* __restrict__ val, int E) {
    int e = blockIdx.x * 256 + threadIdx.x;
    if (e < E) {
        int s = src[e], d = dst[e];
        int pos = atomicAdd(&cursor[d], 1);
        col[pos] = s;
        val[pos] = rsd[s] * rsd[d];
    }
}

// ---------------- GEMM: H = X @ W ----------------
// BM=64 rows/block, full COUT width, BK=32 k-tile, 256 threads, 4x4/8x4 reg block.
template <int COUT>
__launch_bounds__(256)
__global__ void k_gemm(const float* __restrict__ X, const float* __restrict__ W,
                       float* __restrict__ H, int nrows) {
    constexpr int BM = 64, BK = 32, TN = 4;
    constexpr int CG = COUT / TN;
    constexpr int RG = 256 / CG;
    constexpr int TM = BM / RG;
    constexpr int BMP = 68;

    __shared__ float Xs[BK][BMP];   // transposed: Xs[k][row]
    __shared__ float Ws[BK][COUT];

    const int tid = threadIdx.x;
    const int tx = tid % CG;
    const int ty = tid / CG;
    const int r0 = blockIdx.x * BM;

    float acc[TM][TN];
#pragma unroll
    for (int i = 0; i < TM; ++i)
#pragma unroll
        for (int j = 0; j < TN; ++j) acc[i][j] = 0.0f;

    for (int kb = 0; kb < K_DIM; kb += BK) {
        __syncthreads();
        {
            int r = tid >> 3, kq = tid & 7;
#pragma unroll
            for (int p = 0; p < 2; ++p) {
                int rr = r + p * 32;
                int grow = r0 + rr;
                if (grow >= nrows) grow = nrows - 1;
                float4 v = *(const float4*)&X[(size_t)grow * K_DIM + kb + kq * 4];
                Xs[kq * 4 + 0][rr] = v.x;
                Xs[kq * 4 + 1][rr] = v.y;
                Xs[kq * 4 + 2][rr] = v.z;
                Xs[kq * 4 + 3][rr] = v.w;
            }
        }
        {
            constexpr int F4 = COUT / 4;
            constexpr int RP = 256 / F4;
            int wq = tid % F4, wr = tid / F4;
#pragma unroll
            for (int p = 0; p < BK / RP; ++p) {
                int krow = wr + p * RP;
                *(float4*)&Ws[krow][wq * 4] =
                    *(const float4*)&W[(size_t)(kb + krow) * COUT + wq * 4];
            }
        }
        __syncthreads();
#pragma unroll
        for (int kk = 0; kk < BK; ++kk) {
            float4 b4 = *(const float4*)&Ws[kk][tx * TN];
            float a[TM];
#pragma unroll
            for (int i = 0; i < TM; i += 4) {
                float4 a4 = *(const float4*)&Xs[kk][ty * TM + i];
                a[i] = a4.x; a[i + 1] = a4.y; a[i + 2] = a4.z; a[i + 3] = a4.w;
            }
#pragma unroll
            for (int i = 0; i < TM; ++i) {
                acc[i][0] += a[i] * b4.x;
                acc[i][1] += a[i] * b4.y;
                acc[i][2] += a[i] * b4.z;
                acc[i][3] += a[i] * b4.w;
            }
        }
    }

#pragma unroll
    for (int i = 0; i < TM; ++i) {
        int row = r0 + ty * TM + i;
        if (row < nrows)
            *(float4*)&H[(size_t)row * COUT + tx * TN] =
                make_float4(acc[i][0], acc[i][1], acc[i][2], acc[i][3]);
    }
}

// ---------------- CSR gather-reduce aggregation ----------------
// OUT[i,:] = relu?( H[i,:]*invd[i] + bias + sum_{e in row i} H[col[e],:]*val[e] )
// TPN = C/4 threads per node, float4 per thread; one store per element.
template <int C, bool RELU>
__launch_bounds__(256)
__global__ void k_aggregate(const float* __restrict__ H, const int* __restrict__ rowptr,
                            const int* __restrict__ col, const float* __restrict__ val,
                            const float* __restrict__ invd, const float* __restrict__ bias,
                            float* __restrict__ OUT, int n) {
    constexpr int TPN = C / 4;            // 32 (C=128) or 16 (C=64)
    constexpr int NPB = 256 / TPN;        // nodes per block: 8 or 16
    const int node = blockIdx.x * NPB + threadIdx.x / TPN;
    const int c = (threadIdx.x % TPN) * 4;
    if (node >= n) return;

    const float4 b4 = *(const float4*)&bias[c];
    float4 h4 = *(const float4*)&H[(size_t)node * C + c];
    const float idg = invd[node];
    float4 acc = make_float4(h4.x * idg + b4.x, h4.y * idg + b4.y,
                             h4.z * idg + b4.z, h4.w * idg + b4.w);

    const int beg = rowptr[node], end = rowptr[node + 1];
    for (int e = beg; e < end; ++e) {
        int s = col[e];
        float w = val[e];
        float4 v = *(const float4*)&H[(size_t)s * C + c];
        acc.x += v.x * w; acc.y += v.y * w; acc.z += v.z * w; acc.w += v.w * w;
    }
    if (RELU) {
        acc.x = fmaxf(acc.x, 0.0f); acc.y = fmaxf(acc.y, 0.0f);
        acc.z = fmaxf(acc.z, 0.0f); acc.w = fmaxf(acc.w, 0.0f);
    }
    *(float4*)&OUT[(size_t)node * C + c] = acc;
}

// ---------------- launch ----------------

extern "C" void kernel_launch(void* const* d_in, const int* in_sizes, int n_in,
                              void* d_out, int out_size, void* d_ws, size_t ws_size,
                              hipStream_t stream) {
    const float* x  = (const float*)d_in[0];
    const int*   ei = (const int*)d_in[1];
    const float* W1 = (const float*)d_in[2];
    const float* b1 = (const float*)d_in[3];
    const float* W2 = (const float*)d_in[4];
    const float* b2 = (const float*)d_in[5];
    const float* W3 = (const float*)d_in[6];
    const float* b3 = (const float*)d_in[7];

    const int N = in_sizes[0] / K_DIM;   // 50000
    const int E = in_sizes[1] / 2;       // 640000
    const int* srcv = ei;
    const int* dstv = ei + E;

    char* ws = (char*)d_ws;
    size_t off = 0;
    auto alloc = [&](size_t bytes) {
        char* p = ws + off;
        off += (bytes + 255) & ~(size_t)255;
        return p;
    };
    int*   cnt    = (int*)alloc((size_t)N * 4);
    int*   rowptr = (int*)alloc((size_t)(N + 1) * 4);
    int*   cursor = (int*)alloc((size_t)N * 4);
    int*   bsum   = (int*)alloc(256 * 4);
    float* rsd    = (float*)alloc((size_t)N * 4);
    float* invd   = (float*)alloc((size_t)N * 4);
    int*   col    = (int*)alloc((size_t)E * 4);
    float* val    = (float*)alloc((size_t)E * 4);
    float* bufH   = (float*)alloc((size_t)N * K_DIM * 4);
    float* bufA   = (float*)alloc((size_t)N * K_DIM * 4);
    float* out    = (float*)d_out;

    const int gN  = (N + 255) / 256;
    const int gE  = (E + 255) / 256;
    const int gb  = (N + 63) / 64;
    const int nb  = gN;                        // scan blocks (196 <= 256)
    const int gA128 = (N + 7) / 8;             // aggregate C=128: 8 nodes/block
    const int gA64  = (N + 15) / 16;           // aggregate C=64: 16 nodes/block

    // CSR build (once, shared by all 3 layers)
    k_zero_int<<<gN, 256, 0, stream>>>(cnt, N);
    k_count<<<gE, 256, 0, stream>>>(dstv, cnt, E);
    k_norms<<<gN, 256, 0, stream>>>(cnt, rsd, invd, N);
    k_scan_block<<<nb, 256, 0, stream>>>(cnt, rowptr, bsum, N);
    k_scan_bsums<<<1, 256, 0, stream>>>(bsum, nb);
    k_scan_add<<<gN, 256, 0, stream>>>(rowptr, cursor, bsum, N, E);
    k_fill<<<gE, 256, 0, stream>>>(srcv, dstv, rsd, cursor, col, val, E);

    // layer 1: x -> bufA (relu)
    k_gemm<128><<<gb, 256, 0, stream>>>(x, W1, bufH, N);
    k_aggregate<128, true><<<gA128, 256, 0, stream>>>(bufH, rowptr, col, val, invd, b1, bufA, N);

    // layer 2: bufA -> bufA (relu)
    k_gemm<128><<<gb, 256, 0, stream>>>(bufA, W2, bufH, N);
    k_aggregate<128, true><<<gA128, 256, 0, stream>>>(bufH, rowptr, col, val, invd, b2, bufA, N);

    // layer 3: bufA -> d_out (no relu)
    k_gemm<64><<<gb, 256, 0, stream>>>(bufA, W3, bufH, N);
    k_aggregate<64, false><<<gA64, 256, 0, stream>>>(bufH, rowptr, col, val, invd, b3, out, N);
}

// Round 3
// 310.258 us; speedup vs baseline: 2.9479x; 1.1856x over previous
//
#include <hip/hip_runtime.h>

// GCN 3-layer forward on MI355X — round 3: bf16 gather table + fused partials.
//
// R2 post-mortem: aggregates are gather-bytes-bound (327 MB requested, 153 MB
// past L2, VALUBusy 11%). This round:
//  - Hb[s] = bf16(H[s] * rsd[s]) is the gather table (half the bytes, val[]
//    eliminated; coefficient completes as rsd[dst] * sum).
//  - GEMM epilogue writes the f32 partial (H*invd + bias) straight into the
//    layer output buffer; aggregate RMWs it (adds rsd[dst]*sum, fused ReLU).
//    Self-loop term stays full f32 for accuracy.
//  - gather loop unrolled x2 for MLP.

#define K_DIM 128

__device__ __forceinline__ unsigned short f2bf(float x) {
    unsigned u = __float_as_uint(x);
    return (unsigned short)((u + 0x7fffu + ((u >> 16) & 1u)) >> 16);
}

// ---------------- degree / CSR build ----------------

__global__ void k_zero_int(int* __restrict__ p, int n) {
    int i = blockIdx.x * 256 + threadIdx.x;
    if (i < n) p[i] = 0;
}

__global__ void k_count(const int* __restrict__ dst, int* __restrict__ cnt, int E) {
    int e = blockIdx.x * 256 + threadIdx.x;
    if (e < E) atomicAdd(&cnt[dst[e]], 1);
}

__global__ void k_norms(const int* __restrict__ cnt, float* __restrict__ rsd,
                        float* __restrict__ invd, int n) {
    int i = blockIdx.x * 256 + threadIdx.x;
    if (i < n) {
        float dg = (float)cnt[i] + 1.0f;   // +1 self-loop
        rsd[i]  = rsqrtf(dg);
        invd[i] = 1.0f / dg;
    }
}

__global__ void k_scan_block(const int* __restrict__ cnt, int* __restrict__ rowptr,
                             int* __restrict__ bsum, int n) {
    __shared__ int s[256];
    int t = threadIdx.x;
    int i = blockIdx.x * 256 + t;
    int x = (i < n) ? cnt[i] : 0;
    s[t] = x;
    __syncthreads();
#pragma unroll
    for (int d = 1; d < 256; d <<= 1) {
        int v = (t >= d) ? s[t - d] : 0;
        __syncthreads();
        s[t] += v;
        __syncthreads();
    }
    if (i < n) rowptr[i] = s[t] - x;        // exclusive
    if (t == 255) bsum[blockIdx.x] = s[255];
}

__global__ void k_scan_bsums(int* __restrict__ bsum, int nb) {
    __shared__ int s[256];
    int t = threadIdx.x;
    int x = (t < nb) ? bsum[t] : 0;
    s[t] = x;
    __syncthreads();
#pragma unroll
    for (int d = 1; d < 256; d <<= 1) {
        int v = (t >= d) ? s[t - d] : 0;
        __syncthreads();
        s[t] += v;
        __syncthreads();
    }
    if (t < nb) bsum[t] = s[t] - x;         // exclusive
}

__global__ void k_scan_add(int* __restrict__ rowptr, int* __restrict__ cursor,
                           const int* __restrict__ bsum, int n, int E) {
    int i = blockIdx.x * 256 + threadIdx.x;
    if (i < n) {
        int v = rowptr[i] + bsum[i >> 8];
        rowptr[i] = v;
        cursor[i] = v;
    }
    if (i == 0) rowptr[n] = E;
}

__global__ void k_fill(const int* __restrict__ src, const int* __restrict__ dst,
                       int* __restrict__ cursor, int* __restrict__ col, int E) {
    int e = blockIdx.x * 256 + threadIdx.x;
    if (e < E) {
        int d = dst[e];
        int pos = atomicAdd(&cursor[d], 1);
        col[pos] = src[e];
    }
}

// ---------------- GEMM: H = X @ W, fused epilogue ----------------
// Writes: Hb[row,:]  = bf16(H * rsd[row])      (gather table)
//         OUT[row,:] = H * invd[row] + bias    (f32 partial; aggregate RMWs)
// In-place safe when OUT aliases X (block reads only its own rows first).
template <int COUT>
__launch_bounds__(256)
__global__ void k_gemm(const float* __restrict__ X, const float* __restrict__ W,
                       const float* __restrict__ bias, const float* __restrict__ rsd,
                       const float* __restrict__ invd,
                       unsigned short* __restrict__ Hb, float* __restrict__ OUT,
                       int nrows) {
    constexpr int BM = 64, BK = 32, TN = 4;
    constexpr int CG = COUT / TN;
    constexpr int RG = 256 / CG;
    constexpr int TM = BM / RG;
    constexpr int BMP = 68;

    __shared__ float Xs[BK][BMP];   // transposed: Xs[k][row]
    __shared__ float Ws[BK][COUT];

    const int tid = threadIdx.x;
    const int tx = tid % CG;
    const int ty = tid / CG;
    const int r0 = blockIdx.x * BM;

    float acc[TM][TN];
#pragma unroll
    for (int i = 0; i < TM; ++i)
#pragma unroll
        for (int j = 0; j < TN; ++j) acc[i][j] = 0.0f;

    const float4 b4 = *(const float4*)&bias[tx * TN];

    for (int kb = 0; kb < K_DIM; kb += BK) {
        __syncthreads();
        {
            int r = tid >> 3, kq = tid & 7;
#pragma unroll
            for (int p = 0; p < 2; ++p) {
                int rr = r + p * 32;
                int grow = r0 + rr;
                if (grow >= nrows) grow = nrows - 1;
                float4 v = *(const float4*)&X[(size_t)grow * K_DIM + kb + kq * 4];
                Xs[kq * 4 + 0][rr] = v.x;
                Xs[kq * 4 + 1][rr] = v.y;
                Xs[kq * 4 + 2][rr] = v.z;
                Xs[kq * 4 + 3][rr] = v.w;
            }
        }
        {
            constexpr int F4 = COUT / 4;
            constexpr int RP = 256 / F4;
            int wq = tid % F4, wr = tid / F4;
#pragma unroll
            for (int p = 0; p < BK / RP; ++p) {
                int krow = wr + p * RP;
                *(float4*)&Ws[krow][wq * 4] =
                    *(const float4*)&W[(size_t)(kb + krow) * COUT + wq * 4];
            }
        }
        __syncthreads();
#pragma unroll
        for (int kk = 0; kk < BK; ++kk) {
            float4 w4 = *(const float4*)&Ws[kk][tx * TN];
            float a[TM];
#pragma unroll
            for (int i = 0; i < TM; i += 4) {
                float4 a4 = *(const float4*)&Xs[kk][ty * TM + i];
                a[i] = a4.x; a[i + 1] = a4.y; a[i + 2] = a4.z; a[i + 3] = a4.w;
            }
#pragma unroll
            for (int i = 0; i < TM; ++i) {
                acc[i][0] += a[i] * w4.x;
                acc[i][1] += a[i] * w4.y;
                acc[i][2] += a[i] * w4.z;
                acc[i][3] += a[i] * w4.w;
            }
        }
    }

#pragma unroll
    for (int i = 0; i < TM; ++i) {
        int row = r0 + ty * TM + i;
        if (row < nrows) {
            float rs = rsd[row], id = invd[row];
            ushort4 hb;
            hb.x = f2bf(acc[i][0] * rs);
            hb.y = f2bf(acc[i][1] * rs);
            hb.z = f2bf(acc[i][2] * rs);
            hb.w = f2bf(acc[i][3] * rs);
            *(ushort4*)&Hb[(size_t)row * COUT + tx * TN] = hb;
            *(float4*)&OUT[(size_t)row * COUT + tx * TN] =
                make_float4(acc[i][0] * id + b4.x, acc[i][1] * id + b4.y,
                            acc[i][2] * id + b4.z, acc[i][3] * id + b4.w);
        }
    }
}

// ---------------- CSR gather-reduce aggregation (RMW) ----------------
// OUT[i,:] = relu?( OUT[i,:] + rsd[i] * sum_{e in row i} Hb[col[e],:] )
// TPN = C/8 lanes per node, 8 channels (16 B bf16) per lane per gather.
template <int C, bool RELU>
__launch_bounds__(256)
__global__ void k_aggregate(const unsigned short* __restrict__ Hb,
                            const int* __restrict__ rowptr, const int* __restrict__ col,
                            const float* __restrict__ rsd,
                            float* __restrict__ OUT, int n) {
    constexpr int TPN = C / 8;            // 16 (C=128) or 8 (C=64)
    constexpr int NPB = 256 / TPN;        // 16 or 32 nodes per block
    const int node = blockIdx.x * NPB + threadIdx.x / TPN;
    const int c = (threadIdx.x % TPN) * 8;
    if (node >= n) return;

    float acc[8];
#pragma unroll
    for (int j = 0; j < 8; ++j) acc[j] = 0.0f;

    const int beg = rowptr[node], end = rowptr[node + 1];
    int e = beg;
    for (; e + 1 < end; e += 2) {
        int s0 = col[e], s1 = col[e + 1];
        uint4 v0 = *(const uint4*)&Hb[(size_t)s0 * C + c];
        uint4 v1 = *(const uint4*)&Hb[(size_t)s1 * C + c];
        acc[0] += __uint_as_float(v0.x << 16);
        acc[1] += __uint_as_float(v0.x & 0xffff0000u);
        acc[2] += __uint_as_float(v0.y << 16);
        acc[3] += __uint_as_float(v0.y & 0xffff0000u);
        acc[4] += __uint_as_float(v0.z << 16);
        acc[5] += __uint_as_float(v0.z & 0xffff0000u);
        acc[6] += __uint_as_float(v0.w << 16);
        acc[7] += __uint_as_float(v0.w & 0xffff0000u);
        acc[0] += __uint_as_float(v1.x << 16);
        acc[1] += __uint_as_float(v1.x & 0xffff0000u);
        acc[2] += __uint_as_float(v1.y << 16);
        acc[3] += __uint_as_float(v1.y & 0xffff0000u);
        acc[4] += __uint_as_float(v1.z << 16);
        acc[5] += __uint_as_float(v1.z & 0xffff0000u);
        acc[6] += __uint_as_float(v1.w << 16);
        acc[7] += __uint_as_float(v1.w & 0xffff0000u);
    }
    if (e < end) {
        int s0 = col[e];
        uint4 v0 = *(const uint4*)&Hb[(size_t)s0 * C + c];
        acc[0] += __uint_as_float(v0.x << 16);
        acc[1] += __uint_as_float(v0.x & 0xffff0000u);
        acc[2] += __uint_as_float(v0.y << 16);
        acc[3] += __uint_as_float(v0.y & 0xffff0000u);
        acc[4] += __uint_as_float(v0.z << 16);
        acc[5] += __uint_as_float(v0.z & 0xffff0000u);
        acc[6] += __uint_as_float(v0.w << 16);
        acc[7] += __uint_as_float(v0.w & 0xffff0000u);
    }

    const float rs = rsd[node];
    float* po = &OUT[(size_t)node * C + c];
    float4 p0 = *(const float4*)&po[0];
    float4 p1 = *(const float4*)&po[4];
    float r0 = p0.x + rs * acc[0], r1 = p0.y + rs * acc[1];
    float r2 = p0.z + rs * acc[2], r3 = p0.w + rs * acc[3];
    float r4 = p1.x + rs * acc[4], r5 = p1.y + rs * acc[5];
    float r6 = p1.z + rs * acc[6], r7 = p1.w + rs * acc[7];
    if (RELU) {
        r0 = fmaxf(r0, 0.0f); r1 = fmaxf(r1, 0.0f);
        r2 = fmaxf(r2, 0.0f); r3 = fmaxf(r3, 0.0f);
        r4 = fmaxf(r4, 0.0f); r5 = fmaxf(r5, 0.0f);
        r6 = fmaxf(r6, 0.0f); r7 = fmaxf(r7, 0.0f);
    }
    *(float4*)&po[0] = make_float4(r0, r1, r2, r3);
    *(float4*)&po[4] = make_float4(r4, r5, r6, r7);
}

// ---------------- launch ----------------

extern "C" void kernel_launch(void* const* d_in, const int* in_sizes, int n_in,
                              void* d_out, int out_size, void* d_ws, size_t ws_size,
                              hipStream_t stream) {
    const float* x  = (const float*)d_in[0];
    const int*   ei = (const int*)d_in[1];
    const float* W1 = (const float*)d_in[2];
    const float* b1 = (const float*)d_in[3];
    const float* W2 = (const float*)d_in[4];
    const float* b2 = (const float*)d_in[5];
    const float* W3 = (const float*)d_in[6];
    const float* b3 = (const float*)d_in[7];

    const int N = in_sizes[0] / K_DIM;   // 50000
    const int E = in_sizes[1] / 2;       // 640000
    const int* srcv = ei;
    const int* dstv = ei + E;

    char* ws = (char*)d_ws;
    size_t off = 0;
    auto alloc = [&](size_t bytes) {
        char* p = ws + off;
        off += (bytes + 255) & ~(size_t)255;
        return p;
    };
    int*   cnt    = (int*)alloc((size_t)N * 4);
    int*   rowptr = (int*)alloc((size_t)(N + 1) * 4);
    int*   cursor = (int*)alloc((size_t)N * 4);
    int*   bsum   = (int*)alloc(256 * 4);
    float* rsd    = (float*)alloc((size_t)N * 4);
    float* invd   = (float*)alloc((size_t)N * 4);
    int*   col    = (int*)alloc((size_t)E * 4);
    unsigned short* Hb = (unsigned short*)alloc((size_t)N * K_DIM * 2);
    float* bufA   = (float*)alloc((size_t)N * K_DIM * 4);
    float* out    = (float*)d_out;

    const int gN  = (N + 255) / 256;
    const int gE  = (E + 255) / 256;
    const int gb  = (N + 63) / 64;
    const int nb  = gN;
    const int gA128 = (N + 15) / 16;   // C=128: 16 nodes/block
    const int gA64  = (N + 31) / 32;   // C=64: 32 nodes/block

    // CSR build (once, shared by all 3 layers)
    k_zero_int<<<gN, 256, 0, stream>>>(cnt, N);
    k_count<<<gE, 256, 0, stream>>>(dstv, cnt, E);
    k_norms<<<gN, 256, 0, stream>>>(cnt, rsd, invd, N);
    k_scan_block<<<nb, 256, 0, stream>>>(cnt, rowptr, bsum, N);
    k_scan_bsums<<<1, 256, 0, stream>>>(bsum, nb);
    k_scan_add<<<gN, 256, 0, stream>>>(rowptr, cursor, bsum, N, E);
    k_fill<<<gE, 256, 0, stream>>>(srcv, dstv, cursor, col, E);

    // layer 1: x -> bufA (relu)
    k_gemm<128><<<gb, 256, 0, stream>>>(x, W1, b1, rsd, invd, Hb, bufA, N);
    k_aggregate<128, true><<<gA128, 256, 0, stream>>>(Hb, rowptr, col, rsd, bufA, N);

    // layer 2: bufA -> bufA (in-place safe)
    k_gemm<128><<<gb, 256, 0, stream>>>(bufA, W2, b2, rsd, invd, Hb, bufA, N);
    k_aggregate<128, true><<<gA128, 256, 0, stream>>>(Hb, rowptr, col, rsd, bufA, N);

    // layer 3: bufA -> d_out (no relu)
    k_gemm<64><<<gb, 256, 0, stream>>>(bufA, W3, b3, rsd, invd, Hb, out, N);
    k_aggregate<64, false><<<gA64, 256, 0, stream>>>(Hb, rowptr, col, rsd, out, N);
}